// Round 16
// baseline (159.758 us; speedup 1.0000x reference)
//
#include <hip/hip_runtime.h>
#include <hip/hip_bf16.h>
#include <stddef.h>

#define NB 8
#define NC 256
#define NL 2048

typedef __attribute__((ext_vector_type(8))) short s16x8;
typedef __attribute__((ext_vector_type(4))) float f32x4;

__device__ __forceinline__ short f2bs(float x){
  __hip_bfloat16 h = __float2bfloat16(x);
  return __builtin_bit_cast(short, h);
}
__device__ __forceinline__ float bs2f(short x){
  unsigned u = ((unsigned)(unsigned short)x) << 16;
  return __builtin_bit_cast(float, u);
}

#define MFMA16(a,b,c) __builtin_amdgcn_mfma_f32_16x16x32_bf16((a),(b),(c),0,0,0)

// ---------------- fused: GroupNorm partial sums (blocks 0..511) + weight prep (512..1535) ----------------
__global__ __launch_bounds__(256) void k_stats_prep(const float* __restrict__ x, float* __restrict__ gpart,
                                                    const float* __restrict__ wq, const float* __restrict__ wk,
                                                    const float* __restrict__ wv, const float* __restrict__ wo,
                                                    short* __restrict__ wout){
  const int t = threadIdx.x;
  if (blockIdx.x >= 512){
    int idx = (blockIdx.x - 512) * 256 + t;        // 0..262143
    int which = idx >> 16;
    int off = idx & 65535;
    const float* src = (which == 0) ? wq : (which == 1) ? wk : (which == 2) ? wv : wo;
    float sc = (which == 0) ? 0.0625f : 1.0f;      // attn scale C^-0.5 folded into Wq
    wout[idx] = f2bs(src[off] * sc);
    return;
  }
  const int idx = blockIdx.x;
  const float4* base = (const float4*)(x + (size_t)idx * 8192);
  float s = 0.f, ss = 0.f;
  for (int i = t; i < 2048; i += 256){
    float4 v = base[i];
    s  += v.x + v.y + v.z + v.w;
    ss += v.x*v.x + v.y*v.y + v.z*v.z + v.w*v.w;
  }
  #pragma unroll
  for (int m = 32; m; m >>= 1){ s += __shfl_down(s, m); ss += __shfl_down(ss, m); }
  __shared__ float red[8];
  if ((t & 63) == 0){ red[t >> 6] = s; red[4 + (t >> 6)] = ss; }
  __syncthreads();
  if (t == 0){
    gpart[idx * 2 + 0] = red[0] + red[1] + red[2] + red[3];
    gpart[idx * 2 + 1] = red[4] + red[5] + red[6] + red[7];
  }
}

// ---------------- GroupNorm phase 2: normalize + transpose -> ht[b][l][c] ----------------
__global__ __launch_bounds__(256) void k_gapply(const float* __restrict__ x, const float* __restrict__ gamma,
                                                const float* __restrict__ beta, const float* __restrict__ gpart,
                                                short* __restrict__ ht){
  const int idx = blockIdx.x;
  const int bg = idx >> 3, lt8 = idx & 7;
  const int b = bg >> 3, g = bg & 7;
  float S = 0.f, SS = 0.f;
  #pragma unroll
  for (int s2 = 0; s2 < 8; ++s2){ S += gpart[(bg * 8 + s2) * 2]; SS += gpart[(bg * 8 + s2) * 2 + 1]; }
  const float mu = S * (1.f / 65536.f);
  const float var = SS * (1.f / 65536.f) - mu * mu;
  const float rstd = rsqrtf(var + 1e-5f);
  const float* xg = x + (size_t)bg * 65536;
  const int t = threadIdx.x;
  const int cc = t >> 3, lch = t & 7;
  const int c = g * 32 + cc;
  const float gsc = gamma[c] * rstd;
  const float gbi = beta[c] - mu * gsc;
  __shared__ short tile[64 * 33];                 // padded to kill bank conflicts
  const int ll_s = t & 63, cg = t >> 6;
  for (int lt = 0; lt < 4; ++lt){
    const int l0 = lt8 * 256 + lt * 64;
    const float4* rp = (const float4*)(xg + (size_t)cc * NL + l0 + lch * 8);
    float4 a = rp[0], bv = rp[1];
    float vals[8] = {a.x, a.y, a.z, a.w, bv.x, bv.y, bv.z, bv.w};
    short o[8];
    #pragma unroll
    for (int e = 0; e < 8; ++e) o[e] = f2bs(vals[e] * gsc + gbi);
    __syncthreads();
    #pragma unroll
    for (int e = 0; e < 8; ++e) tile[(lch * 8 + e) * 33 + cc] = o[e];
    __syncthreads();
    s16x8 pk;
    #pragma unroll
    for (int e = 0; e < 8; ++e) pk[e] = tile[ll_s * 33 + cg * 8 + e];
    *(s16x8*)(ht + ((size_t)(b * NL) + l0 + ll_s) * NC + g * 32 + cg * 8) = pk;
  }
}

// ---------------- fused q,k,v conv, 128x128 tiles (m93 pattern: 64x64/wave, 4x4 frags) ----------------
__global__ __launch_bounds__(256) void k_conv_qkv(const short* __restrict__ ht, const short* __restrict__ wbf,
                                                  const float* __restrict__ bq, const float* __restrict__ bk,
                                                  const float* __restrict__ bv,
                                                  short* __restrict__ qt, short* __restrict__ kt,
                                                  short* __restrict__ vt){
  const int z = blockIdx.z;
  const int b = z & 7, which = z >> 3;
  const int lane = threadIdx.x & 63, wid = threadIdx.x >> 6;
  const int wr = wid >> 1, wc = wid & 1;
  const int kgrp = (lane >> 4) * 8;
  const short* aptr;
  const short* bptr;
  int m0, n0;
  if (which < 2){
    m0 = blockIdx.y * 128 + wr * 64;             // l rows
    n0 = blockIdx.x * 128 + wc * 64;             // o cols
    aptr = ht + ((size_t)(b * NL) + m0 + (lane & 15)) * NC + kgrp;
    bptr = wbf + (which ? 65536 : 0) + (size_t)(n0 + (lane & 15)) * NC + kgrp;
  } else {
    const int idx = blockIdx.y * 2 + blockIdx.x; // 0..31
    m0 = (idx & 1) * 128 + wr * 64;              // o rows
    n0 = (idx >> 1) * 128 + wc * 64;             // l cols
    aptr = wbf + 2 * 65536 + (size_t)(m0 + (lane & 15)) * NC + kgrp;
    bptr = ht + ((size_t)(b * NL) + n0 + (lane & 15)) * NC + kgrp;
  }
  f32x4 acc[4][4];
  #pragma unroll
  for (int i = 0; i < 4; ++i){
    #pragma unroll
    for (int j = 0; j < 4; ++j){ f32x4 z2 = {0.f,0.f,0.f,0.f}; acc[i][j] = z2; }
  }
  for (int kk = 0; kk < 256; kk += 32){
    s16x8 af[4], bfr[4];
    #pragma unroll
    for (int mf = 0; mf < 4; ++mf) af[mf] = *(const s16x8*)(aptr + (size_t)(mf * 16) * NC + kk);
    #pragma unroll
    for (int nf = 0; nf < 4; ++nf) bfr[nf] = *(const s16x8*)(bptr + (size_t)(nf * 16) * NC + kk);
    #pragma unroll
    for (int mf = 0; mf < 4; ++mf)
      #pragma unroll
      for (int nf = 0; nf < 4; ++nf)
        acc[mf][nf] = MFMA16(af[mf], bfr[nf], acc[mf][nf]);
  }
  if (which < 2){
    const float* bias = which ? bk : bq;
    const float bsc = which ? 1.0f : 0.0625f;
    short* outp = which ? kt : qt;
    #pragma unroll
    for (int nf = 0; nf < 4; ++nf){
      const int oc = n0 + nf * 16 + (lane & 15);
      const float bb = bias[oc] * bsc;
      #pragma unroll
      for (int mf = 0; mf < 4; ++mf){
        #pragma unroll
        for (int r = 0; r < 4; ++r){
          const int lr = m0 + mf * 16 + (lane >> 4) * 4 + r;
          outp[((size_t)(b * NL) + lr) * NC + oc] = f2bs(acc[mf][nf][r] + bb);
        }
      }
    }
  } else {
    #pragma unroll
    for (int mf = 0; mf < 4; ++mf){
      #pragma unroll
      for (int r = 0; r < 4; ++r){
        const int orow = m0 + mf * 16 + (lane >> 4) * 4 + r;
        const float bb = bv[orow];
        #pragma unroll
        for (int nf = 0; nf < 4; ++nf){
          const int lcol = n0 + nf * 16 + (lane & 15);
          vt[((size_t)(b * NC) + orow) * NL + lcol] = f2bs(acc[mf][nf][r] + bb);
        }
      }
    }
  }
}

// ---------------- flash attention, KVBLK=32, 3 blocks/CU attempt ----------------
// Round-15 analysis: nothing saturated (Mfma 20 / VALU 23 / LDS ~40%) -> latency-bound
// at 2 waves/SIMD. KVBLK=32 relaxes BOTH caps: LDS 72->36 KB (3 blocks fit) and regs
// (sf 16->8, less staging state) -> peak ~165 <= 170 = 512/3 -> launch_bounds(256,3).
// KVBLK=32 addressing/swizzles copied verbatim from rounds 9/10 (both passed refcheck;
// round-10 slowness was the (256,4) spill, not this layout). Schedule: round-7 3-barrier
// with vmcnt(4) (4-instr STAGE). Defer-max (T13) kept (sf[2] form).
// Failure signatures: FETCH >> 12 MB = spill; occupancy ~19% = regs > 170.
__global__ __launch_bounds__(256, 3) void k_flash(const short* __restrict__ qt, const short* __restrict__ kt,
                                                  const short* __restrict__ v, short* __restrict__ po,
                                                  float* __restrict__ ml){
  const int flat = blockIdx.x;
  const int b = flat & 7;
  const int rest = flat >> 3;
  const int h = rest & 1;
  const int i0 = (rest >> 1) * 64;
  const int lane = threadIdx.x & 63, wid = threadIdx.x >> 6;
  __shared__ short k_lds[32 * 256];               // 16 KB
  __shared__ short v_lds[256 * 32];               // 16 KB
  __shared__ short plds[4][512];                  // 4 KB, per-wave 16x32 P tile
  short* pl = plds[wid];
  const int arow = lane & 15, kg = lane >> 4;

  const short* qp = qt + ((size_t)(b * NL) + i0 + wid * 16 + arow) * NC + kg * 8;
  s16x8 qf[8];
  #pragma unroll
  for (int kc = 0; kc < 8; ++kc) qf[kc] = *(const s16x8*)(qp + kc * 32);

  f32x4 oacc[16];
  #pragma unroll
  for (int i = 0; i < 16; ++i){ f32x4 z = {0.f,0.f,0.f,0.f}; oacc[i] = z; }
  float m_r[4], l_r[4];
  #pragma unroll
  for (int r = 0; r < 4; ++r){ m_r[r] = -3.0e38f; l_r[r] = 0.f; }

  // --- staging: 4 global_load_lds (16B) per thread per tile per matrix ---
  auto STAGE_K = [&](int jt){
    const int j0 = jt * 32;
    #pragma unroll
    for (int t = 0; t < 4; ++t){
      const int i = wid * 4 + t;                  // 16 wave-instrs, 2 K-rows each
      const int r = 2 * i + (lane >> 5);
      const int wb = (lane & 31) * 16;            // byte offset within 512B row
      const short* src = kt + ((size_t)(b * NL) + j0 + r) * NC + ((wb ^ ((r & 15) << 4)) >> 1);
      __builtin_amdgcn_global_load_lds((const __attribute__((address_space(1))) void*)src,
                                       (__attribute__((address_space(3))) void*)&k_lds[i * 512], 16, 0, 0);
    }
  };
  auto STAGE_V = [&](int jt){
    const int j0 = jt * 32;
    #pragma unroll
    for (int t = 0; t < 4; ++t){
      const int i = wid * 4 + t;                  // 16 wave-instrs, 16 V-rows (64B) each
      const int rc = 16 * i + (lane >> 2);
      const int wb = (lane & 3) * 16;             // byte offset within 64B row
      const short* src = v + ((size_t)(b * NC) + rc) * NL + j0 + ((wb ^ (((rc >> 1) & 3) << 4)) >> 1);
      __builtin_amdgcn_global_load_lds((const __attribute__((address_space(1))) void*)src,
                                       (__attribute__((address_space(3))) void*)&v_lds[i * 512], 16, 0, 0);
    }
  };

  const int jb0 = h * 32, jend = jb0 + 32;        // 32 tiles of 32 cols each
  STAGE_K(jb0);
  STAGE_V(jb0);
  asm volatile("s_waitcnt vmcnt(0)" ::: "memory");
  __builtin_amdgcn_s_barrier();
  __builtin_amdgcn_sched_barrier(0);

  for (int jt = jb0; jt < jend; ++jt){
    // ---- QK^T from k_lds ----
    f32x4 sf[2];
    #pragma unroll
    for (int nf = 0; nf < 2; ++nf){ f32x4 z = {0.f,0.f,0.f,0.f}; sf[nf] = z; }
    __builtin_amdgcn_s_setprio(1);
    #pragma unroll
    for (int kc = 0; kc < 8; ++kc){
      #pragma unroll
      for (int nf = 0; nf < 2; ++nf){
        const int r = nf * 16 + arow;
        s16x8 kf = *(const s16x8*)&k_lds[r * 256 + (((kc * 64 + kg * 16) ^ ((r & 15) << 4)) >> 1)];
        sf[nf] = MFMA16(qf[kc], kf, sf[nf]);
      }
    }
    __builtin_amdgcn_s_setprio(0);
    // ---- online softmax with defer-max (T13, THR=8) ----
    float mx[4];
    #pragma unroll
    for (int r = 0; r < 4; ++r){
      float m2 = fmaxf(sf[0][r], sf[1][r]);
      #pragma unroll
      for (int d = 1; d < 16; d <<= 1) m2 = fmaxf(m2, __shfl_xor(m2, d));
      mx[r] = m2;
    }
    const int ok = (mx[0] <= m_r[0] + 8.f) & (mx[1] <= m_r[1] + 8.f) &
                   (mx[2] <= m_r[2] + 8.f) & (mx[3] <= m_r[3] + 8.f);
    if (!__all(ok)){
      float corr[4];
      #pragma unroll
      for (int r = 0; r < 4; ++r){
        const float mn = fmaxf(m_r[r], mx[r]);
        corr[r] = __expf(m_r[r] - mn);
        m_r[r] = mn;
        l_r[r] *= corr[r];
      }
      #pragma unroll
      for (int i = 0; i < 16; ++i){
        f32x4 t = oacc[i];
        t[0] *= corr[0]; t[1] *= corr[1]; t[2] *= corr[2]; t[3] *= corr[3];
        oacc[i] = t;
      }
    }
    #pragma unroll
    for (int r = 0; r < 4; ++r){
      float rs = 0.f;
      #pragma unroll
      for (int nf = 0; nf < 2; ++nf){
        float p = __expf(sf[nf][r] - m_r[r]);
        sf[nf][r] = p;
        rs += p;
      }
      #pragma unroll
      for (int d = 1; d < 16; d <<= 1) rs += __shfl_xor(rs, d);
      l_r[r] += rs;
    }
    asm volatile("s_waitcnt vmcnt(0)" ::: "memory");
    __builtin_amdgcn_s_barrier();                 // K(t) reads done + V(t) visible
    __builtin_amdgcn_sched_barrier(0);
    if (jt + 1 < jend) STAGE_K(jt + 1);           // hides under P+PV

    // ---- P -> per-wave LDS (16x32, 64B-row granule swizzle) ----
    #pragma unroll
    for (int r = 0; r < 4; ++r){
      const int rowp = kg * 4 + r;
      const int swz = ((rowp >> 1) & 3) << 3;
      #pragma unroll
      for (int nf = 0; nf < 2; ++nf){
        const int col = nf * 16 + arow;
        pl[rowp * 32 + (col ^ swz)] = f2bs(sf[nf][r]);
      }
    }
    // ---- PV from v_lds (K=32, single slice) ----
    __builtin_amdgcn_s_setprio(1);
    {
      s16x8 pa = *(const s16x8*)(pl + arow * 32 + ((kg * 8) ^ (((arow >> 1) & 3) << 3)));
      #pragma unroll
      for (int nf2 = 0; nf2 < 16; ++nf2){
        const int rc = nf2 * 16 + arow;
        s16x8 vf = *(const s16x8*)&v_lds[rc * 32 + (((kg * 16) ^ (((rc >> 1) & 3) << 4)) >> 1)];
        oacc[nf2] = MFMA16(pa, vf, oacc[nf2]);
      }
    }
    __builtin_amdgcn_s_setprio(0);
    __builtin_amdgcn_s_barrier();                 // V(t) reads done
    __builtin_amdgcn_sched_barrier(0);
    if (jt + 1 < jend) STAGE_V(jt + 1);           // hides under next QK+softmax
    asm volatile("s_waitcnt vmcnt(4)" ::: "memory");  // K(t+1) landed (V(t+1) in flight)
    __builtin_amdgcn_s_barrier();
    __builtin_amdgcn_sched_barrier(0);
  }

  // ---- epilogue: write unnormalized partial O (bf16) + m,l per row ----
  short* pob = po + (size_t)h * 4194304 + ((size_t)(b * NL) + i0 + wid * 16) * NC;
  #pragma unroll
  for (int r = 0; r < 4; ++r){
    const int irow = kg * 4 + r;
    #pragma unroll
    for (int nf2 = 0; nf2 < 16; ++nf2){
      pob[(size_t)irow * NC + nf2 * 16 + arow] = f2bs(oacc[nf2][r]);
    }
    if (arow == 0){
      const size_t Rg = (size_t)h * 16384 + (size_t)(b * NL) + i0 + wid * 16 + irow;
      ml[Rg * 2 + 0] = m_r[r];
      ml[Rg * 2 + 1] = l_r[r];
    }
  }
}

// ---------------- final conv + fused split-KV merge + bias + residual ----------------
// 128x128 block tile, 64x64/wave, 4x4 frags.
__global__ __launch_bounds__(256) void k_final(const short* __restrict__ po, const float* __restrict__ ml,
                                               const short* __restrict__ wo, const float* __restrict__ bo,
                                               const float* __restrict__ x, float* __restrict__ out){
  const int b = blockIdx.z;
  const int lane = threadIdx.x & 63, wid = threadIdx.x >> 6;
  const int wr = wid >> 1, wc = wid & 1;
  const int o0 = blockIdx.y * 128 + wr * 64;   // m-base
  const int i0 = blockIdx.x * 128 + wc * 64;   // n-base
  const int kgrp = (lane >> 4) * 8;
  const short* aptr = wo + (size_t)(o0 + (lane & 15)) * NC + kgrp;
  float wgt[4][2], winv[4];
  size_t rbase[4];
  #pragma unroll
  for (int nf = 0; nf < 4; ++nf){
    const int Rg = b * NL + i0 + nf * 16 + (lane & 15);
    rbase[nf] = (size_t)Rg * NC + kgrp;
    const float m0 = ml[(size_t)Rg * 2],             l0 = ml[(size_t)Rg * 2 + 1];
    const float m1 = ml[((size_t)16384 + Rg) * 2],   l1 = ml[((size_t)16384 + Rg) * 2 + 1];
    const float mm = fmaxf(m0, m1);
    wgt[nf][0] = __expf(m0 - mm);
    wgt[nf][1] = __expf(m1 - mm);
    winv[nf] = 1.f / (l0 * wgt[nf][0] + l1 * wgt[nf][1]);
  }
  f32x4 acc[4][4];
  #pragma unroll
  for (int i = 0; i < 4; ++i){
    #pragma unroll
    for (int j = 0; j < 4; ++j){ f32x4 z = {0.f,0.f,0.f,0.f}; acc[i][j] = z; }
  }
  for (int kk = 0; kk < 256; kk += 32){
    s16x8 af[4], bfr[4];
    #pragma unroll
    for (int mf = 0; mf < 4; ++mf) af[mf] = *(const s16x8*)(aptr + (size_t)(mf * 16) * NC + kk);
    #pragma unroll
    for (int nf = 0; nf < 4; ++nf){
      s16x8 p0 = *(const s16x8*)(po + rbase[nf] + kk);
      s16x8 p1 = *(const s16x8*)(po + (size_t)4194304 + rbase[nf] + kk);
      #pragma unroll
      for (int e = 0; e < 8; ++e)
        bfr[nf][e] = f2bs((wgt[nf][0] * bs2f(p0[e]) + wgt[nf][1] * bs2f(p1[e])) * winv[nf]);
    }
    #pragma unroll
    for (int mf = 0; mf < 4; ++mf)
      #pragma unroll
      for (int nf = 0; nf < 4; ++nf)
        acc[mf][nf] = MFMA16(af[mf], bfr[nf], acc[mf][nf]);
  }
  #pragma unroll
  for (int mf = 0; mf < 4; ++mf){
    #pragma unroll
    for (int r = 0; r < 4; ++r){
      const int orow = o0 + mf * 16 + (lane >> 4) * 4 + r;
      const float bb = bo[orow];
      #pragma unroll
      for (int nf = 0; nf < 4; ++nf){
        const int icol = i0 + nf * 16 + (lane & 15);
        const size_t idx = ((size_t)(b * NC) + orow) * NL + icol;
        out[idx] = acc[mf][nf][r] + bb + x[idx];
      }
    }
  }
}

extern "C" void kernel_launch(void* const* d_in, const int* in_sizes, int n_in,
                              void* d_out, int out_size, void* d_ws, size_t ws_size,
                              hipStream_t stream){
  const float* x     = (const float*)d_in[0];
  const float* gamma = (const float*)d_in[1];
  const float* beta  = (const float*)d_in[2];
  const float* Wq    = (const float*)d_in[3];
  const float* bq    = (const float*)d_in[4];
  const float* Wk    = (const float*)d_in[5];
  const float* bk    = (const float*)d_in[6];
  const float* Wv    = (const float*)d_in[7];
  const float* bv    = (const float*)d_in[8];
  const float* Wo    = (const float*)d_in[9];
  const float* bo    = (const float*)d_in[10];
  float* out = (float*)d_out;

  char* ws = (char*)d_ws;
  // layout (bytes): wbf 512K | ht 8M | qt 8M | kt 8M | v 8M | po 16M | ml 256K | gp 4K
  short* wbf = (short*)ws;
  short* ht  = (short*)(ws + (size_t)524288);
  short* qt  = (short*)(ws + (size_t)524288 + 8388608);
  short* ktp = (short*)(ws + (size_t)524288 + 2 * 8388608);
  short* vp  = (short*)(ws + (size_t)524288 + 3 * 8388608);
  short* pop = (short*)(ws + (size_t)524288 + 4 * 8388608);
  float* mlp = (float*)(ws + (size_t)524288 + 6 * 8388608);
  float* gpp = (float*)(ws + (size_t)524288 + 6 * 8388608 + 262144);

  k_stats_prep<<<1536, 256, 0, stream>>>(x, gpp, Wq, Wk, Wv, Wo, wbf);
  k_gapply<<<512, 256, 0, stream>>>(x, gamma, beta, gpp, ht);
  k_conv_qkv<<<dim3(2, 16, 24), 256, 0, stream>>>(ht, wbf, bq, bk, bv, qt, ktp, vp);
  k_flash  <<<dim3(512), 256, 0, stream>>>(qt, ktp, vp, pop, mlp);
  k_final  <<<dim3(16, 2, 8), 256, 0, stream>>>(pop, mlp, wbf + 3 * 65536, bo, x, out);
}

// Round 18
// 128.028 us; speedup vs baseline: 1.2478x; 1.2478x over previous
//
#include <hip/hip_runtime.h>
#include <hip/hip_bf16.h>
#include <stddef.h>

#define NB 8
#define NC 256
#define NL 2048

typedef __attribute__((ext_vector_type(8))) short s16x8;
typedef __attribute__((ext_vector_type(4))) float f32x4;

__device__ __forceinline__ short f2bs(float x){
  __hip_bfloat16 h = __float2bfloat16(x);
  return __builtin_bit_cast(short, h);
}
__device__ __forceinline__ float bs2f(short x){
  unsigned u = ((unsigned)(unsigned short)x) << 16;
  return __builtin_bit_cast(float, u);
}

#define MFMA16(a,b,c) __builtin_amdgcn_mfma_f32_16x16x32_bf16((a),(b),(c),0,0,0)

// ---------------- fused: GroupNorm partial sums (blocks 0..511) + weight prep (512..1535) ----------------
__global__ __launch_bounds__(256) void k_stats_prep(const float* __restrict__ x, float* __restrict__ gpart,
                                                    const float* __restrict__ wq, const float* __restrict__ wk,
                                                    const float* __restrict__ wv, const float* __restrict__ wo,
                                                    short* __restrict__ wout){
  const int t = threadIdx.x;
  if (blockIdx.x >= 512){
    int idx = (blockIdx.x - 512) * 256 + t;        // 0..262143
    int which = idx >> 16;
    int off = idx & 65535;
    const float* src = (which == 0) ? wq : (which == 1) ? wk : (which == 2) ? wv : wo;
    float sc = (which == 0) ? 0.0625f : 1.0f;      // attn scale C^-0.5 folded into Wq
    wout[idx] = f2bs(src[off] * sc);
    return;
  }
  const int idx = blockIdx.x;
  const float4* base = (const float4*)(x + (size_t)idx * 8192);
  float s = 0.f, ss = 0.f;
  for (int i = t; i < 2048; i += 256){
    float4 v = base[i];
    s  += v.x + v.y + v.z + v.w;
    ss += v.x*v.x + v.y*v.y + v.z*v.z + v.w*v.w;
  }
  #pragma unroll
  for (int m = 32; m; m >>= 1){ s += __shfl_down(s, m); ss += __shfl_down(ss, m); }
  __shared__ float red[8];
  if ((t & 63) == 0){ red[t >> 6] = s; red[4 + (t >> 6)] = ss; }
  __syncthreads();
  if (t == 0){
    gpart[idx * 2 + 0] = red[0] + red[1] + red[2] + red[3];
    gpart[idx * 2 + 1] = red[4] + red[5] + red[6] + red[7];
  }
}

// ---------------- GroupNorm phase 2: normalize + transpose -> ht[b][l][c] ----------------
__global__ __launch_bounds__(256) void k_gapply(const float* __restrict__ x, const float* __restrict__ gamma,
                                                const float* __restrict__ beta, const float* __restrict__ gpart,
                                                short* __restrict__ ht){
  const int idx = blockIdx.x;
  const int bg = idx >> 3, lt8 = idx & 7;
  const int b = bg >> 3, g = bg & 7;
  float S = 0.f, SS = 0.f;
  #pragma unroll
  for (int s2 = 0; s2 < 8; ++s2){ S += gpart[(bg * 8 + s2) * 2]; SS += gpart[(bg * 8 + s2) * 2 + 1]; }
  const float mu = S * (1.f / 65536.f);
  const float var = SS * (1.f / 65536.f) - mu * mu;
  const float rstd = rsqrtf(var + 1e-5f);
  const float* xg = x + (size_t)bg * 65536;
  const int t = threadIdx.x;
  const int cc = t >> 3, lch = t & 7;
  const int c = g * 32 + cc;
  const float gsc = gamma[c] * rstd;
  const float gbi = beta[c] - mu * gsc;
  __shared__ short tile[64 * 33];                 // padded to kill bank conflicts
  const int ll_s = t & 63, cg = t >> 6;
  for (int lt = 0; lt < 4; ++lt){
    const int l0 = lt8 * 256 + lt * 64;
    const float4* rp = (const float4*)(xg + (size_t)cc * NL + l0 + lch * 8);
    float4 a = rp[0], bv = rp[1];
    float vals[8] = {a.x, a.y, a.z, a.w, bv.x, bv.y, bv.z, bv.w};
    short o[8];
    #pragma unroll
    for (int e = 0; e < 8; ++e) o[e] = f2bs(vals[e] * gsc + gbi);
    __syncthreads();
    #pragma unroll
    for (int e = 0; e < 8; ++e) tile[(lch * 8 + e) * 33 + cc] = o[e];
    __syncthreads();
    s16x8 pk;
    #pragma unroll
    for (int e = 0; e < 8; ++e) pk[e] = tile[ll_s * 33 + cg * 8 + e];
    *(s16x8*)(ht + ((size_t)(b * NL) + l0 + ll_s) * NC + g * 32 + cg * 8) = pk;
  }
}

// ---------------- fused q,k,v conv, 128x128 tiles (m93 pattern: 64x64/wave, 4x4 frags) ----------------
__global__ __launch_bounds__(256) void k_conv_qkv(const short* __restrict__ ht, const short* __restrict__ wbf,
                                                  const float* __restrict__ bq, const float* __restrict__ bk,
                                                  const float* __restrict__ bv,
                                                  short* __restrict__ qt, short* __restrict__ kt,
                                                  short* __restrict__ vt){
  const int z = blockIdx.z;
  const int b = z & 7, which = z >> 3;
  const int lane = threadIdx.x & 63, wid = threadIdx.x >> 6;
  const int wr = wid >> 1, wc = wid & 1;
  const int kgrp = (lane >> 4) * 8;
  const short* aptr;
  const short* bptr;
  int m0, n0;
  if (which < 2){
    m0 = blockIdx.y * 128 + wr * 64;             // l rows
    n0 = blockIdx.x * 128 + wc * 64;             // o cols
    aptr = ht + ((size_t)(b * NL) + m0 + (lane & 15)) * NC + kgrp;
    bptr = wbf + (which ? 65536 : 0) + (size_t)(n0 + (lane & 15)) * NC + kgrp;
  } else {
    const int idx = blockIdx.y * 2 + blockIdx.x; // 0..31
    m0 = (idx & 1) * 128 + wr * 64;              // o rows
    n0 = (idx >> 1) * 128 + wc * 64;             // l cols
    aptr = wbf + 2 * 65536 + (size_t)(m0 + (lane & 15)) * NC + kgrp;
    bptr = ht + ((size_t)(b * NL) + n0 + (lane & 15)) * NC + kgrp;
  }
  f32x4 acc[4][4];
  #pragma unroll
  for (int i = 0; i < 4; ++i){
    #pragma unroll
    for (int j = 0; j < 4; ++j){ f32x4 z2 = {0.f,0.f,0.f,0.f}; acc[i][j] = z2; }
  }
  for (int kk = 0; kk < 256; kk += 32){
    s16x8 af[4], bfr[4];
    #pragma unroll
    for (int mf = 0; mf < 4; ++mf) af[mf] = *(const s16x8*)(aptr + (size_t)(mf * 16) * NC + kk);
    #pragma unroll
    for (int nf = 0; nf < 4; ++nf) bfr[nf] = *(const s16x8*)(bptr + (size_t)(nf * 16) * NC + kk);
    #pragma unroll
    for (int mf = 0; mf < 4; ++mf)
      #pragma unroll
      for (int nf = 0; nf < 4; ++nf)
        acc[mf][nf] = MFMA16(af[mf], bfr[nf], acc[mf][nf]);
  }
  if (which < 2){
    const float* bias = which ? bk : bq;
    const float bsc = which ? 1.0f : 0.0625f;
    short* outp = which ? kt : qt;
    #pragma unroll
    for (int nf = 0; nf < 4; ++nf){
      const int oc = n0 + nf * 16 + (lane & 15);
      const float bb = bias[oc] * bsc;
      #pragma unroll
      for (int mf = 0; mf < 4; ++mf){
        #pragma unroll
        for (int r = 0; r < 4; ++r){
          const int lr = m0 + mf * 16 + (lane >> 4) * 4 + r;
          outp[((size_t)(b * NL) + lr) * NC + oc] = f2bs(acc[mf][nf][r] + bb);
        }
      }
    }
  } else {
    #pragma unroll
    for (int mf = 0; mf < 4; ++mf){
      #pragma unroll
      for (int r = 0; r < 4; ++r){
        const int orow = m0 + mf * 16 + (lane >> 4) * 4 + r;
        const float bb = bv[orow];
        #pragma unroll
        for (int nf = 0; nf < 4; ++nf){
          const int lcol = n0 + nf * 16 + (lane & 15);
          vt[((size_t)(b * NC) + orow) * NL + lcol] = f2bs(acc[mf][nf][r] + bb);
        }
      }
    }
  }
}

// ---------------- flash attention, LDS-staged, block-level split-KV x2 + defer-max ----------------
// FROZEN at round-14/15 measured best (67.5-67.9 us, 3x confirmed): KVBLK=64,
// K+V staged, 72 KB LDS, (256,2), 3-barrier schedule, defer-max.
// Refuted alternatives (do not retry): (256,4)/(256,3) -> accumulator spill
// (r10: FETCH 12->459 MB; r16: WRITE 16.6->33 MB); V-direct-from-L2 -> 2.4x worse
// (r13); KVBLK=32 -> 2x barrier overhead + spill (r16); dbuf 1-barrier -> neutral
// (r8). Register floor ~208+/wave hard-caps TLP at 2 waves/SIMD.
__global__ __launch_bounds__(256, 2) void k_flash(const short* __restrict__ qt, const short* __restrict__ kt,
                                                  const short* __restrict__ v, short* __restrict__ po,
                                                  float* __restrict__ ml){
  const int flat = blockIdx.x;
  const int b = flat & 7;
  const int rest = flat >> 3;
  const int h = rest & 1;
  const int i0 = (rest >> 1) * 64;
  const int lane = threadIdx.x & 63, wid = threadIdx.x >> 6;
  __shared__ short k_lds[64 * 256];               // 32 KB
  __shared__ short v_lds[256 * 64];               // 32 KB
  __shared__ short plds[4][1024];                 // 8 KB, per-wave 16x64 P tile
  short* pl = plds[wid];
  const int arow = lane & 15, kg = lane >> 4;

  const short* qp = qt + ((size_t)(b * NL) + i0 + wid * 16 + arow) * NC + kg * 8;
  s16x8 qf[8];
  #pragma unroll
  for (int kc = 0; kc < 8; ++kc) qf[kc] = *(const s16x8*)(qp + kc * 32);

  f32x4 oacc[16];
  #pragma unroll
  for (int i = 0; i < 16; ++i){ f32x4 z = {0.f,0.f,0.f,0.f}; oacc[i] = z; }
  float m_r[4], l_r[4];
  #pragma unroll
  for (int r = 0; r < 4; ++r){ m_r[r] = -3.0e38f; l_r[r] = 0.f; }

  auto STAGE_K = [&](int jt){
    const int j0 = jt * 64;
    #pragma unroll
    for (int t = 0; t < 8; ++t){
      const int i = wid * 8 + t;
      const int r = 2 * i + (lane >> 5);
      const int wb = (lane & 31) * 16;
      const short* src = kt + ((size_t)(b * NL) + j0 + r) * NC + ((wb ^ ((r & 15) << 4)) >> 1);
      __builtin_amdgcn_global_load_lds((const __attribute__((address_space(1))) void*)src,
                                       (__attribute__((address_space(3))) void*)&k_lds[i * 512], 16, 0, 0);
    }
  };
  auto STAGE_V = [&](int jt){
    const int j0 = jt * 64;
    #pragma unroll
    for (int t = 0; t < 8; ++t){
      const int i = wid * 8 + t;
      const int rc = 8 * i + (lane >> 3);
      const int wb = (lane & 7) * 16;
      const short* src = v + ((size_t)(b * NC) + rc) * NL + j0 + ((wb ^ ((rc & 7) << 4)) >> 1);
      __builtin_amdgcn_global_load_lds((const __attribute__((address_space(1))) void*)src,
                                       (__attribute__((address_space(3))) void*)&v_lds[i * 512], 16, 0, 0);
    }
  };

  const int jb0 = h * 16, jend = jb0 + 16;
  STAGE_K(jb0);
  STAGE_V(jb0);
  asm volatile("s_waitcnt vmcnt(0)" ::: "memory");
  __builtin_amdgcn_s_barrier();
  __builtin_amdgcn_sched_barrier(0);

  for (int jt = jb0; jt < jend; ++jt){
    // ---- QK^T from k_lds ----
    f32x4 sf[4];
    #pragma unroll
    for (int nf = 0; nf < 4; ++nf){ f32x4 z = {0.f,0.f,0.f,0.f}; sf[nf] = z; }
    __builtin_amdgcn_s_setprio(1);
    #pragma unroll
    for (int kc = 0; kc < 8; ++kc){
      #pragma unroll
      for (int nf = 0; nf < 4; ++nf){
        const int r = nf * 16 + arow;
        s16x8 kf = *(const s16x8*)&k_lds[r * 256 + (((kc * 64 + kg * 16) ^ ((arow & 15) << 4)) >> 1)];
        sf[nf] = MFMA16(qf[kc], kf, sf[nf]);
      }
    }
    __builtin_amdgcn_s_setprio(0);
    // ---- online softmax with defer-max (T13, THR=8) ----
    float mx[4];
    #pragma unroll
    for (int r = 0; r < 4; ++r){
      float m2 = fmaxf(fmaxf(sf[0][r], sf[1][r]), fmaxf(sf[2][r], sf[3][r]));
      #pragma unroll
      for (int d = 1; d < 16; d <<= 1) m2 = fmaxf(m2, __shfl_xor(m2, d));
      mx[r] = m2;
    }
    const int ok = (mx[0] <= m_r[0] + 8.f) & (mx[1] <= m_r[1] + 8.f) &
                   (mx[2] <= m_r[2] + 8.f) & (mx[3] <= m_r[3] + 8.f);
    if (!__all(ok)){
      float corr[4];
      #pragma unroll
      for (int r = 0; r < 4; ++r){
        const float mn = fmaxf(m_r[r], mx[r]);
        corr[r] = __expf(m_r[r] - mn);
        m_r[r] = mn;
        l_r[r] *= corr[r];
      }
      #pragma unroll
      for (int i = 0; i < 16; ++i){
        f32x4 t = oacc[i];
        t[0] *= corr[0]; t[1] *= corr[1]; t[2] *= corr[2]; t[3] *= corr[3];
        oacc[i] = t;
      }
    }
    #pragma unroll
    for (int r = 0; r < 4; ++r){
      float rs = 0.f;
      #pragma unroll
      for (int nf = 0; nf < 4; ++nf){
        float p = __expf(sf[nf][r] - m_r[r]);
        sf[nf][r] = p;
        rs += p;
      }
      #pragma unroll
      for (int d = 1; d < 16; d <<= 1) rs += __shfl_xor(rs, d);
      l_r[r] += rs;
    }
    asm volatile("s_waitcnt vmcnt(0)" ::: "memory");
    __builtin_amdgcn_s_barrier();                 // K(t) reads done + V(t) visible
    __builtin_amdgcn_sched_barrier(0);
    if (jt + 1 < jend) STAGE_K(jt + 1);           // hides under P+PV

    // ---- P -> per-wave LDS (XOR swizzle) ----
    #pragma unroll
    for (int r = 0; r < 4; ++r){
      const int rowp = kg * 4 + r;
      const int swz = (rowp & 7) << 3;
      #pragma unroll
      for (int nf = 0; nf < 4; ++nf){
        const int col = nf * 16 + arow;
        pl[rowp * 64 + (col ^ swz)] = f2bs(sf[nf][r]);
      }
    }
    // ---- PV from v_lds ----
    __builtin_amdgcn_s_setprio(1);
    #pragma unroll
    for (int kc2 = 0; kc2 < 2; ++kc2){
      const int swz2 = (arow & 7) << 3;
      s16x8 pa = *(const s16x8*)(pl + arow * 64 + ((kc2 * 32 + kg * 8) ^ swz2));
      #pragma unroll
      for (int nf2 = 0; nf2 < 16; ++nf2){
        const int rc = nf2 * 16 + arow;
        s16x8 vf = *(const s16x8*)&v_lds[rc * 64 + (((kc2 * 64 + kg * 16) ^ ((rc & 7) << 4)) >> 1)];
        oacc[nf2] = MFMA16(pa, vf, oacc[nf2]);
      }
    }
    __builtin_amdgcn_s_setprio(0);
    __builtin_amdgcn_s_barrier();                 // V(t) reads done
    __builtin_amdgcn_sched_barrier(0);
    if (jt + 1 < jend) STAGE_V(jt + 1);           // hides under next QK+softmax
    asm volatile("s_waitcnt vmcnt(8)" ::: "memory");  // K(t+1) landed (V(t+1) in flight)
    __builtin_amdgcn_s_barrier();
    __builtin_amdgcn_sched_barrier(0);
  }

  // ---- epilogue: write unnormalized partial O (bf16) + m,l per row ----
  short* pob = po + (size_t)h * 4194304 + ((size_t)(b * NL) + i0 + wid * 16) * NC;
  #pragma unroll
  for (int r = 0; r < 4; ++r){
    const int irow = kg * 4 + r;
    #pragma unroll
    for (int nf2 = 0; nf2 < 16; ++nf2){
      pob[(size_t)irow * NC + nf2 * 16 + arow] = f2bs(oacc[nf2][r]);
    }
    if (arow == 0){
      const size_t Rg = (size_t)h * 16384 + (size_t)(b * NL) + i0 + wid * 16 + irow;
      ml[Rg * 2 + 0] = m_r[r];
      ml[Rg * 2 + 1] = l_r[r];
    }
  }
}

// ---------------- final conv + fused split-KV merge + bias + residual ----------------
// 128x128 block tile, 64x64/wave, 4x4 frags.
__global__ __launch_bounds__(256) void k_final(const short* __restrict__ po, const float* __restrict__ ml,
                                               const short* __restrict__ wo, const float* __restrict__ bo,
                                               const float* __restrict__ x, float* __restrict__ out){
  const int b = blockIdx.z;
  const int lane = threadIdx.x & 63, wid = threadIdx.x >> 6;
  const int wr = wid >> 1, wc = wid & 1;
  const int o0 = blockIdx.y * 128 + wr * 64;   // m-base
  const int i0 = blockIdx.x * 128 + wc * 64;   // n-base
  const int kgrp = (lane >> 4) * 8;
  const short* aptr = wo + (size_t)(o0 + (lane & 15)) * NC + kgrp;
  float wgt[4][2], winv[4];
  size_t rbase[4];
  #pragma unroll
  for (int nf = 0; nf < 4; ++nf){
    const int Rg = b * NL + i0 + nf * 16 + (lane & 15);
    rbase[nf] = (size_t)Rg * NC + kgrp;
    const float m0 = ml[(size_t)Rg * 2],             l0 = ml[(size_t)Rg * 2 + 1];
    const float m1 = ml[((size_t)16384 + Rg) * 2],   l1 = ml[((size_t)16384 + Rg) * 2 + 1];
    const float mm = fmaxf(m0, m1);
    wgt[nf][0] = __expf(m0 - mm);
    wgt[nf][1] = __expf(m1 - mm);
    winv[nf] = 1.f / (l0 * wgt[nf][0] + l1 * wgt[nf][1]);
  }
  f32x4 acc[4][4];
  #pragma unroll
  for (int i = 0; i < 4; ++i){
    #pragma unroll
    for (int j = 0; j < 4; ++j){ f32x4 z = {0.f,0.f,0.f,0.f}; acc[i][j] = z; }
  }
  for (int kk = 0; kk < 256; kk += 32){
    s16x8 af[4], bfr[4];
    #pragma unroll
    for (int mf = 0; mf < 4; ++mf) af[mf] = *(const s16x8*)(aptr + (size_t)(mf * 16) * NC + kk);
    #pragma unroll
    for (int nf = 0; nf < 4; ++nf){
      s16x8 p0 = *(const s16x8*)(po + rbase[nf] + kk);
      s16x8 p1 = *(const s16x8*)(po + (size_t)4194304 + rbase[nf] + kk);
      #pragma unroll
      for (int e = 0; e < 8; ++e)
        bfr[nf][e] = f2bs((wgt[nf][0] * bs2f(p0[e]) + wgt[nf][1] * bs2f(p1[e])) * winv[nf]);
    }
    #pragma unroll
    for (int mf = 0; mf < 4; ++mf)
      #pragma unroll
      for (int nf = 0; nf < 4; ++nf)
        acc[mf][nf] = MFMA16(af[mf], bfr[nf], acc[mf][nf]);
  }
  #pragma unroll
  for (int mf = 0; mf < 4; ++mf){
    #pragma unroll
    for (int r = 0; r < 4; ++r){
      const int orow = o0 + mf * 16 + (lane >> 4) * 4 + r;
      const float bb = bo[orow];
      #pragma unroll
      for (int nf = 0; nf < 4; ++nf){
        const int icol = i0 + nf * 16 + (lane & 15);
        const size_t idx = ((size_t)(b * NC) + orow) * NL + icol;
        out[idx] = acc[mf][nf][r] + bb + x[idx];
      }
    }
  }
}

extern "C" void kernel_launch(void* const* d_in, const int* in_sizes, int n_in,
                              void* d_out, int out_size, void* d_ws, size_t ws_size,
                              hipStream_t stream){
  const float* x     = (const float*)d_in[0];
  const float* gamma = (const float*)d_in[1];
  const float* beta  = (const float*)d_in[2];
  const float* Wq    = (const float*)d_in[3];
  const float* bq    = (const float*)d_in[4];
  const float* Wk    = (const float*)d_in[5];
  const float* bk    = (const float*)d_in[6];
  const float* Wv    = (const float*)d_in[7];
  const float* bv    = (const float*)d_in[8];
  const float* Wo    = (const float*)d_in[9];
  const float* bo    = (const float*)d_in[10];
  float* out = (float*)d_out;

  char* ws = (char*)d_ws;
  // layout (bytes): wbf 512K | ht 8M | qt 8M | kt 8M | v 8M | po 16M | ml 256K | gp 4K
  short* wbf = (short*)ws;
  short* ht  = (short*)(ws + (size_t)524288);
  short* qt  = (short*)(ws + (size_t)524288 + 8388608);
  short* ktp = (short*)(ws + (size_t)524288 + 2 * 8388608);
  short* vp  = (short*)(ws + (size_t)524288 + 3 * 8388608);
  short* pop = (short*)(ws + (size_t)524288 + 4 * 8388608);
  float* mlp = (float*)(ws + (size_t)524288 + 6 * 8388608);
  float* gpp = (float*)(ws + (size_t)524288 + 6 * 8388608 + 262144);

  k_stats_prep<<<1536, 256, 0, stream>>>(x, gpp, Wq, Wk, Wv, Wo, wbf);
  k_gapply<<<512, 256, 0, stream>>>(x, gamma, beta, gpp, ht);
  k_conv_qkv<<<dim3(2, 16, 24), 256, 0, stream>>>(ht, wbf, bq, bk, bv, qt, ktp, vp);
  k_flash  <<<dim3(512), 256, 0, stream>>>(qt, ktp, vp, pop, mlp);
  k_final  <<<dim3(16, 2, 8), 256, 0, stream>>>(pop, mlp, wbf + 3 * 65536, bo, x, out);
}

// Round 19
// 120.793 us; speedup vs baseline: 1.3226x; 1.0599x over previous
//
#include <hip/hip_runtime.h>
#include <hip/hip_bf16.h>
#include <stddef.h>

#define NB 8
#define NC 256
#define NL 2048

typedef __attribute__((ext_vector_type(8))) short s16x8;
typedef __attribute__((ext_vector_type(4))) float f32x4;

__device__ __forceinline__ short f2bs(float x){
  __hip_bfloat16 h = __float2bfloat16(x);
  return __builtin_bit_cast(short, h);
}
__device__ __forceinline__ float bs2f(short x){
  unsigned u = ((unsigned)(unsigned short)x) << 16;
  return __builtin_bit_cast(float, u);
}

#define MFMA16(a,b,c) __builtin_amdgcn_mfma_f32_16x16x32_bf16((a),(b),(c),0,0,0)

// ---------------- fused: GroupNorm partial sums (blocks 0..511) + weight prep (512..1535) ----------------
__global__ __launch_bounds__(256) void k_stats_prep(const float* __restrict__ x, float* __restrict__ gpart,
                                                    const float* __restrict__ wq, const float* __restrict__ wk,
                                                    const float* __restrict__ wv, const float* __restrict__ wo,
                                                    short* __restrict__ wout){
  const int t = threadIdx.x;
  if (blockIdx.x >= 512){
    int idx = (blockIdx.x - 512) * 256 + t;        // 0..262143
    int which = idx >> 16;
    int off = idx & 65535;
    const float* src = (which == 0) ? wq : (which == 1) ? wk : (which == 2) ? wv : wo;
    float sc = (which == 0) ? 0.0625f : 1.0f;      // attn scale C^-0.5 folded into Wq
    wout[idx] = f2bs(src[off] * sc);
    return;
  }
  const int idx = blockIdx.x;
  const float4* base = (const float4*)(x + (size_t)idx * 8192);
  float s = 0.f, ss = 0.f;
  for (int i = t; i < 2048; i += 256){
    float4 v = base[i];
    s  += v.x + v.y + v.z + v.w;
    ss += v.x*v.x + v.y*v.y + v.z*v.z + v.w*v.w;
  }
  #pragma unroll
  for (int m = 32; m; m >>= 1){ s += __shfl_down(s, m); ss += __shfl_down(ss, m); }
  __shared__ float red[8];
  if ((t & 63) == 0){ red[t >> 6] = s; red[4 + (t >> 6)] = ss; }
  __syncthreads();
  if (t == 0){
    gpart[idx * 2 + 0] = red[0] + red[1] + red[2] + red[3];
    gpart[idx * 2 + 1] = red[4] + red[5] + red[6] + red[7];
  }
}

// ---------------- GroupNorm phase 2: normalize + transpose -> ht[b][l][c] ----------------
__global__ __launch_bounds__(256) void k_gapply(const float* __restrict__ x, const float* __restrict__ gamma,
                                                const float* __restrict__ beta, const float* __restrict__ gpart,
                                                short* __restrict__ ht){
  const int idx = blockIdx.x;
  const int bg = idx >> 3, lt8 = idx & 7;
  const int b = bg >> 3, g = bg & 7;
  float S = 0.f, SS = 0.f;
  #pragma unroll
  for (int s2 = 0; s2 < 8; ++s2){ S += gpart[(bg * 8 + s2) * 2]; SS += gpart[(bg * 8 + s2) * 2 + 1]; }
  const float mu = S * (1.f / 65536.f);
  const float var = SS * (1.f / 65536.f) - mu * mu;
  const float rstd = rsqrtf(var + 1e-5f);
  const float* xg = x + (size_t)bg * 65536;
  const int t = threadIdx.x;
  const int cc = t >> 3, lch = t & 7;
  const int c = g * 32 + cc;
  const float gsc = gamma[c] * rstd;
  const float gbi = beta[c] - mu * gsc;
  __shared__ short tile[64 * 33];                 // padded to kill bank conflicts
  const int ll_s = t & 63, cg = t >> 6;
  for (int lt = 0; lt < 4; ++lt){
    const int l0 = lt8 * 256 + lt * 64;
    const float4* rp = (const float4*)(xg + (size_t)cc * NL + l0 + lch * 8);
    float4 a = rp[0], bv = rp[1];
    float vals[8] = {a.x, a.y, a.z, a.w, bv.x, bv.y, bv.z, bv.w};
    short o[8];
    #pragma unroll
    for (int e = 0; e < 8; ++e) o[e] = f2bs(vals[e] * gsc + gbi);
    __syncthreads();
    #pragma unroll
    for (int e = 0; e < 8; ++e) tile[(lch * 8 + e) * 33 + cc] = o[e];
    __syncthreads();
    s16x8 pk;
    #pragma unroll
    for (int e = 0; e < 8; ++e) pk[e] = tile[ll_s * 33 + cg * 8 + e];
    *(s16x8*)(ht + ((size_t)(b * NL) + l0 + ll_s) * NC + g * 32 + cg * 8) = pk;
  }
}

// ---------------- fused q,k,v conv, 128x128 tiles, XCD-pinned (b = flat&7) ----------------
// T1: flat grid 768 so batch b's blocks land on XCD b (round-6 verified mechanism) ->
// ht[b] (1 MB) stays L2-resident across the 3 passes (q,k,v) that each read it.
// rest = flat>>3: which = rest/32 (0=q,1=k,2=v), tile = rest%32.
__global__ __launch_bounds__(256) void k_conv_qkv(const short* __restrict__ ht, const short* __restrict__ wbf,
                                                  const float* __restrict__ bq, const float* __restrict__ bk,
                                                  const float* __restrict__ bv,
                                                  short* __restrict__ qt, short* __restrict__ kt,
                                                  short* __restrict__ vt){
  const int flat = blockIdx.x;
  const int b = flat & 7;
  const int rest = flat >> 3;                    // 0..95
  const int which = rest >> 5;                   // 0..2
  const int tile = rest & 31;                    // 0..31
  const int lane = threadIdx.x & 63, wid = threadIdx.x >> 6;
  const int wr = wid >> 1, wc = wid & 1;
  const int kgrp = (lane >> 4) * 8;
  const short* aptr;
  const short* bptr;
  int m0, n0;
  if (which < 2){
    m0 = (tile >> 1) * 128 + wr * 64;            // l rows (16 tiles)
    n0 = (tile & 1) * 128 + wc * 64;             // o cols (2 tiles)
    aptr = ht + ((size_t)(b * NL) + m0 + (lane & 15)) * NC + kgrp;
    bptr = wbf + (which ? 65536 : 0) + (size_t)(n0 + (lane & 15)) * NC + kgrp;
  } else {
    m0 = (tile & 1) * 128 + wr * 64;             // o rows (2 tiles)
    n0 = (tile >> 1) * 128 + wc * 64;            // l cols (16 tiles)
    aptr = wbf + 2 * 65536 + (size_t)(m0 + (lane & 15)) * NC + kgrp;
    bptr = ht + ((size_t)(b * NL) + n0 + (lane & 15)) * NC + kgrp;
  }
  f32x4 acc[4][4];
  #pragma unroll
  for (int i = 0; i < 4; ++i){
    #pragma unroll
    for (int j = 0; j < 4; ++j){ f32x4 z2 = {0.f,0.f,0.f,0.f}; acc[i][j] = z2; }
  }
  for (int kk = 0; kk < 256; kk += 32){
    s16x8 af[4], bfr[4];
    #pragma unroll
    for (int mf = 0; mf < 4; ++mf) af[mf] = *(const s16x8*)(aptr + (size_t)(mf * 16) * NC + kk);
    #pragma unroll
    for (int nf = 0; nf < 4; ++nf) bfr[nf] = *(const s16x8*)(bptr + (size_t)(nf * 16) * NC + kk);
    #pragma unroll
    for (int mf = 0; mf < 4; ++mf)
      #pragma unroll
      for (int nf = 0; nf < 4; ++nf)
        acc[mf][nf] = MFMA16(af[mf], bfr[nf], acc[mf][nf]);
  }
  if (which < 2){
    const float* bias = which ? bk : bq;
    const float bsc = which ? 1.0f : 0.0625f;
    short* outp = which ? kt : qt;
    #pragma unroll
    for (int nf = 0; nf < 4; ++nf){
      const int oc = n0 + nf * 16 + (lane & 15);
      const float bb = bias[oc] * bsc;
      #pragma unroll
      for (int mf = 0; mf < 4; ++mf){
        #pragma unroll
        for (int r = 0; r < 4; ++r){
          const int lr = m0 + mf * 16 + (lane >> 4) * 4 + r;
          outp[((size_t)(b * NL) + lr) * NC + oc] = f2bs(acc[mf][nf][r] + bb);
        }
      }
    }
  } else {
    #pragma unroll
    for (int mf = 0; mf < 4; ++mf){
      #pragma unroll
      for (int r = 0; r < 4; ++r){
        const int orow = m0 + mf * 16 + (lane >> 4) * 4 + r;
        const float bb = bv[orow];
        #pragma unroll
        for (int nf = 0; nf < 4; ++nf){
          const int lcol = n0 + nf * 16 + (lane & 15);
          vt[((size_t)(b * NC) + orow) * NL + lcol] = f2bs(acc[mf][nf][r] + bb);
        }
      }
    }
  }
}

// ---------------- flash attention, LDS-staged, block-level split-KV x2 + defer-max ----------------
// FROZEN at round-14/15/18 measured best (67.5-67.9 us, 4x confirmed): KVBLK=64,
// K+V staged, 72 KB LDS, (256,2), 3-barrier schedule, defer-max.
// Refuted alternatives (do not retry): (256,4)/(256,3) -> accumulator spill
// (r10/r16); V-direct-from-L2 -> 2.4x worse (r13); KVBLK=32 -> spill + 2x barrier
// overhead (r16); dbuf 1-barrier -> neutral (r8). Register floor ~208+/wave
// hard-caps TLP at 2 waves/SIMD.
__global__ __launch_bounds__(256, 2) void k_flash(const short* __restrict__ qt, const short* __restrict__ kt,
                                                  const short* __restrict__ v, short* __restrict__ po,
                                                  float* __restrict__ ml){
  const int flat = blockIdx.x;
  const int b = flat & 7;
  const int rest = flat >> 3;
  const int h = rest & 1;
  const int i0 = (rest >> 1) * 64;
  const int lane = threadIdx.x & 63, wid = threadIdx.x >> 6;
  __shared__ short k_lds[64 * 256];               // 32 KB
  __shared__ short v_lds[256 * 64];               // 32 KB
  __shared__ short plds[4][1024];                 // 8 KB, per-wave 16x64 P tile
  short* pl = plds[wid];
  const int arow = lane & 15, kg = lane >> 4;

  const short* qp = qt + ((size_t)(b * NL) + i0 + wid * 16 + arow) * NC + kg * 8;
  s16x8 qf[8];
  #pragma unroll
  for (int kc = 0; kc < 8; ++kc) qf[kc] = *(const s16x8*)(qp + kc * 32);

  f32x4 oacc[16];
  #pragma unroll
  for (int i = 0; i < 16; ++i){ f32x4 z = {0.f,0.f,0.f,0.f}; oacc[i] = z; }
  float m_r[4], l_r[4];
  #pragma unroll
  for (int r = 0; r < 4; ++r){ m_r[r] = -3.0e38f; l_r[r] = 0.f; }

  auto STAGE_K = [&](int jt){
    const int j0 = jt * 64;
    #pragma unroll
    for (int t = 0; t < 8; ++t){
      const int i = wid * 8 + t;
      const int r = 2 * i + (lane >> 5);
      const int wb = (lane & 31) * 16;
      const short* src = kt + ((size_t)(b * NL) + j0 + r) * NC + ((wb ^ ((r & 15) << 4)) >> 1);
      __builtin_amdgcn_global_load_lds((const __attribute__((address_space(1))) void*)src,
                                       (__attribute__((address_space(3))) void*)&k_lds[i * 512], 16, 0, 0);
    }
  };
  auto STAGE_V = [&](int jt){
    const int j0 = jt * 64;
    #pragma unroll
    for (int t = 0; t < 8; ++t){
      const int i = wid * 8 + t;
      const int rc = 8 * i + (lane >> 3);
      const int wb = (lane & 7) * 16;
      const short* src = v + ((size_t)(b * NC) + rc) * NL + j0 + ((wb ^ ((rc & 7) << 4)) >> 1);
      __builtin_amdgcn_global_load_lds((const __attribute__((address_space(1))) void*)src,
                                       (__attribute__((address_space(3))) void*)&v_lds[i * 512], 16, 0, 0);
    }
  };

  const int jb0 = h * 16, jend = jb0 + 16;
  STAGE_K(jb0);
  STAGE_V(jb0);
  asm volatile("s_waitcnt vmcnt(0)" ::: "memory");
  __builtin_amdgcn_s_barrier();
  __builtin_amdgcn_sched_barrier(0);

  for (int jt = jb0; jt < jend; ++jt){
    // ---- QK^T from k_lds ----
    f32x4 sf[4];
    #pragma unroll
    for (int nf = 0; nf < 4; ++nf){ f32x4 z = {0.f,0.f,0.f,0.f}; sf[nf] = z; }
    __builtin_amdgcn_s_setprio(1);
    #pragma unroll
    for (int kc = 0; kc < 8; ++kc){
      #pragma unroll
      for (int nf = 0; nf < 4; ++nf){
        const int r = nf * 16 + arow;
        s16x8 kf = *(const s16x8*)&k_lds[r * 256 + (((kc * 64 + kg * 16) ^ ((arow & 15) << 4)) >> 1)];
        sf[nf] = MFMA16(qf[kc], kf, sf[nf]);
      }
    }
    __builtin_amdgcn_s_setprio(0);
    // ---- online softmax with defer-max (T13, THR=8) ----
    float mx[4];
    #pragma unroll
    for (int r = 0; r < 4; ++r){
      float m2 = fmaxf(fmaxf(sf[0][r], sf[1][r]), fmaxf(sf[2][r], sf[3][r]));
      #pragma unroll
      for (int d = 1; d < 16; d <<= 1) m2 = fmaxf(m2, __shfl_xor(m2, d));
      mx[r] = m2;
    }
    const int ok = (mx[0] <= m_r[0] + 8.f) & (mx[1] <= m_r[1] + 8.f) &
                   (mx[2] <= m_r[2] + 8.f) & (mx[3] <= m_r[3] + 8.f);
    if (!__all(ok)){
      float corr[4];
      #pragma unroll
      for (int r = 0; r < 4; ++r){
        const float mn = fmaxf(m_r[r], mx[r]);
        corr[r] = __expf(m_r[r] - mn);
        m_r[r] = mn;
        l_r[r] *= corr[r];
      }
      #pragma unroll
      for (int i = 0; i < 16; ++i){
        f32x4 t = oacc[i];
        t[0] *= corr[0]; t[1] *= corr[1]; t[2] *= corr[2]; t[3] *= corr[3];
        oacc[i] = t;
      }
    }
    #pragma unroll
    for (int r = 0; r < 4; ++r){
      float rs = 0.f;
      #pragma unroll
      for (int nf = 0; nf < 4; ++nf){
        float p = __expf(sf[nf][r] - m_r[r]);
        sf[nf][r] = p;
        rs += p;
      }
      #pragma unroll
      for (int d = 1; d < 16; d <<= 1) rs += __shfl_xor(rs, d);
      l_r[r] += rs;
    }
    asm volatile("s_waitcnt vmcnt(0)" ::: "memory");
    __builtin_amdgcn_s_barrier();                 // K(t) reads done + V(t) visible
    __builtin_amdgcn_sched_barrier(0);
    if (jt + 1 < jend) STAGE_K(jt + 1);           // hides under P+PV

    // ---- P -> per-wave LDS (XOR swizzle) ----
    #pragma unroll
    for (int r = 0; r < 4; ++r){
      const int rowp = kg * 4 + r;
      const int swz = (rowp & 7) << 3;
      #pragma unroll
      for (int nf = 0; nf < 4; ++nf){
        const int col = nf * 16 + arow;
        pl[rowp * 64 + (col ^ swz)] = f2bs(sf[nf][r]);
      }
    }
    // ---- PV from v_lds ----
    __builtin_amdgcn_s_setprio(1);
    #pragma unroll
    for (int kc2 = 0; kc2 < 2; ++kc2){
      const int swz2 = (arow & 7) << 3;
      s16x8 pa = *(const s16x8*)(pl + arow * 64 + ((kc2 * 32 + kg * 8) ^ swz2));
      #pragma unroll
      for (int nf2 = 0; nf2 < 16; ++nf2){
        const int rc = nf2 * 16 + arow;
        s16x8 vf = *(const s16x8*)&v_lds[rc * 64 + (((kc2 * 64 + kg * 16) ^ ((rc & 7) << 4)) >> 1)];
        oacc[nf2] = MFMA16(pa, vf, oacc[nf2]);
      }
    }
    __builtin_amdgcn_s_setprio(0);
    __builtin_amdgcn_s_barrier();                 // V(t) reads done
    __builtin_amdgcn_sched_barrier(0);
    if (jt + 1 < jend) STAGE_V(jt + 1);           // hides under next QK+softmax
    asm volatile("s_waitcnt vmcnt(8)" ::: "memory");  // K(t+1) landed (V(t+1) in flight)
    __builtin_amdgcn_s_barrier();
    __builtin_amdgcn_sched_barrier(0);
  }

  // ---- epilogue: write unnormalized partial O (bf16) + m,l per row ----
  short* pob = po + (size_t)h * 4194304 + ((size_t)(b * NL) + i0 + wid * 16) * NC;
  #pragma unroll
  for (int r = 0; r < 4; ++r){
    const int irow = kg * 4 + r;
    #pragma unroll
    for (int nf2 = 0; nf2 < 16; ++nf2){
      pob[(size_t)irow * NC + nf2 * 16 + arow] = f2bs(oacc[nf2][r]);
    }
    if (arow == 0){
      const size_t Rg = (size_t)h * 16384 + (size_t)(b * NL) + i0 + wid * 16 + irow;
      ml[Rg * 2 + 0] = m_r[r];
      ml[Rg * 2 + 1] = l_r[r];
    }
  }
}

// ---------------- final conv + fused split-KV merge + bias + residual, XCD-pinned ----------------
// T1: flat grid 256, b = flat&7 -> batch b's po/x slices served from XCD b's L2.
// rest = flat>>3: o-tile = rest&1, i-tile = rest>>1. 128x128 tile, 64x64/wave.
__global__ __launch_bounds__(256) void k_final(const short* __restrict__ po, const float* __restrict__ ml,
                                               const short* __restrict__ wo, const float* __restrict__ bo,
                                               const float* __restrict__ x, float* __restrict__ out){
  const int flat = blockIdx.x;
  const int b = flat & 7;
  const int rest = flat >> 3;                    // 0..31
  const int lane = threadIdx.x & 63, wid = threadIdx.x >> 6;
  const int wr = wid >> 1, wc = wid & 1;
  const int o0 = (rest & 1) * 128 + wr * 64;     // m-base (2 o-tiles)
  const int i0 = (rest >> 1) * 128 + wc * 64;    // n-base (16 i-tiles)
  const int kgrp = (lane >> 4) * 8;
  const short* aptr = wo + (size_t)(o0 + (lane & 15)) * NC + kgrp;
  float wgt[4][2], winv[4];
  size_t rbase[4];
  #pragma unroll
  for (int nf = 0; nf < 4; ++nf){
    const int Rg = b * NL + i0 + nf * 16 + (lane & 15);
    rbase[nf] = (size_t)Rg * NC + kgrp;
    const float m0 = ml[(size_t)Rg * 2],             l0 = ml[(size_t)Rg * 2 + 1];
    const float m1 = ml[((size_t)16384 + Rg) * 2],   l1 = ml[((size_t)16384 + Rg) * 2 + 1];
    const float mm = fmaxf(m0, m1);
    wgt[nf][0] = __expf(m0 - mm);
    wgt[nf][1] = __expf(m1 - mm);
    winv[nf] = 1.f / (l0 * wgt[nf][0] + l1 * wgt[nf][1]);
  }
  f32x4 acc[4][4];
  #pragma unroll
  for (int i = 0; i < 4; ++i){
    #pragma unroll
    for (int j = 0; j < 4; ++j){ f32x4 z = {0.f,0.f,0.f,0.f}; acc[i][j] = z; }
  }
  for (int kk = 0; kk < 256; kk += 32){
    s16x8 af[4], bfr[4];
    #pragma unroll
    for (int mf = 0; mf < 4; ++mf) af[mf] = *(const s16x8*)(aptr + (size_t)(mf * 16) * NC + kk);
    #pragma unroll
    for (int nf = 0; nf < 4; ++nf){
      s16x8 p0 = *(const s16x8*)(po + rbase[nf] + kk);
      s16x8 p1 = *(const s16x8*)(po + (size_t)4194304 + rbase[nf] + kk);
      #pragma unroll
      for (int e = 0; e < 8; ++e)
        bfr[nf][e] = f2bs((wgt[nf][0] * bs2f(p0[e]) + wgt[nf][1] * bs2f(p1[e])) * winv[nf]);
    }
    #pragma unroll
    for (int mf = 0; mf < 4; ++mf)
      #pragma unroll
      for (int nf = 0; nf < 4; ++nf)
        acc[mf][nf] = MFMA16(af[mf], bfr[nf], acc[mf][nf]);
  }
  #pragma unroll
  for (int mf = 0; mf < 4; ++mf){
    #pragma unroll
    for (int r = 0; r < 4; ++r){
      const int orow = o0 + mf * 16 + (lane >> 4) * 4 + r;
      const float bb = bo[orow];
      #pragma unroll
      for (int nf = 0; nf < 4; ++nf){
        const int icol = i0 + nf * 16 + (lane & 15);
        const size_t idx = ((size_t)(b * NC) + orow) * NL + icol;
        out[idx] = acc[mf][nf][r] + bb + x[idx];
      }
    }
  }
}

extern "C" void kernel_launch(void* const* d_in, const int* in_sizes, int n_in,
                              void* d_out, int out_size, void* d_ws, size_t ws_size,
                              hipStream_t stream){
  const float* x     = (const float*)d_in[0];
  const float* gamma = (const float*)d_in[1];
  const float* beta  = (const float*)d_in[2];
  const float* Wq    = (const float*)d_in[3];
  const float* bq    = (const float*)d_in[4];
  const float* Wk    = (const float*)d_in[5];
  const float* bk    = (const float*)d_in[6];
  const float* Wv    = (const float*)d_in[7];
  const float* bv    = (const float*)d_in[8];
  const float* Wo    = (const float*)d_in[9];
  const float* bo    = (const float*)d_in[10];
  float* out = (float*)d_out;

  char* ws = (char*)d_ws;
  // layout (bytes): wbf 512K | ht 8M | qt 8M | kt 8M | v 8M | po 16M | ml 256K | gp 4K
  short* wbf = (short*)ws;
  short* ht  = (short*)(ws + (size_t)524288);
  short* qt  = (short*)(ws + (size_t)524288 + 8388608);
  short* ktp = (short*)(ws + (size_t)524288 + 2 * 8388608);
  short* vp  = (short*)(ws + (size_t)524288 + 3 * 8388608);
  short* pop = (short*)(ws + (size_t)524288 + 4 * 8388608);
  float* mlp = (float*)(ws + (size_t)524288 + 6 * 8388608);
  float* gpp = (float*)(ws + (size_t)524288 + 6 * 8388608 + 262144);

  k_stats_prep<<<1536, 256, 0, stream>>>(x, gpp, Wq, Wk, Wv, Wo, wbf);
  k_gapply<<<512, 256, 0, stream>>>(x, gamma, beta, gpp, ht);
  k_conv_qkv<<<dim3(768), 256, 0, stream>>>(ht, wbf, bq, bk, bv, qt, ktp, vp);
  k_flash  <<<dim3(512), 256, 0, stream>>>(qt, ktp, vp, pop, mlp);
  k_final  <<<dim3(256), 256, 0, stream>>>(pop, mlp, wbf + 3 * 65536, bo, x, out);
}